// Round 7
// baseline (708.510 us; speedup 1.0000x reference)
//
#include <hip/hip_runtime.h>
#include <hip/hip_bf16.h>
#include <stdint.h>

#define LATF 256
#define NT 119
#define NNODES 100000
#define NEDGES 400000
#define NBUCK 100352          // 392*256, >= NNODES
#define NT3 12500             // k3 tiles of 32 edges

typedef __attribute__((ext_vector_type(8))) short short8;
typedef __attribute__((ext_vector_type(4))) float f4;

__device__ __forceinline__ float bf2f(short u) {
  union { uint32_t i; float f; } v; v.i = ((uint32_t)(uint16_t)u) << 16; return v.f;
}
__device__ __forceinline__ short f2bf(float f) {
  union { float f; uint32_t i; } v; v.f = f;
  uint32_t r = (v.i + 0x7fffu + ((v.i >> 16) & 1u)) >> 16;
  return (short)(uint16_t)r;
}

// ---------------- prep: cast + build transposed weight layouts ----------------
__global__ __launch_bounds__(256) void prep_kernel(
    const float* __restrict__ lat, const float* __restrict__ pos,
    const float* __restrict__ nW1, const float* __restrict__ tW1, const float* __restrict__ dW1,
    const float* __restrict__ nW2, const float* __restrict__ tW2, const float* __restrict__ dW2,
    const float* __restrict__ nW3, const float* __restrict__ tW3, const float* __restrict__ dW3,
    short* __restrict__ latent_bf, short* __restrict__ pos_bf,
    short* __restrict__ Wtcat, short* __restrict__ Wt2cat,
    short* __restrict__ Wt3n, short* __restrict__ Wt3t, short* __restrict__ Wt3d)
{
  int i = blockIdx.x * 256 + threadIdx.x;
  if (i < 524288) { latent_bf[i] = f2bf(lat[i]); return; }
  i -= 524288;
  if (i < 800000) { pos_bf[i] = f2bf(pos[i]); return; }
  i -= 800000;
  if (i < 1280 * 288) {               // Wtcat[n][k], n-major, K padded 264->288
    int n = i / 288, k = i % 288;
    float v = 0.f;
    if (k < 264) {
      if (n < 256)       v = nW1[k * 256 + n];
      else if (n < 512)  v = tW1[k * 256 + (n - 256)];
      else if (n < 768)  v = tW1[(264 + k) * 256 + (n - 512)];
      else if (n < 1024) v = dW1[k * 256 + (n - 768)];
      else               v = dW1[(264 + k) * 256 + (n - 1024)];
    }
    Wtcat[n * 288 + k] = f2bf(v);
    return;
  }
  i -= 1280 * 288;
  if (i < 384 * 256) {                // Wt2cat[n][k]: rows 0-127 nW2, 128-255 tW2, 256-383 dW2
    int n = i / 256, k = i % 256;
    float v = (n < 128) ? nW2[k * 128 + n] : (n < 256) ? tW2[k * 128 + (n - 128)]
                                                       : dW2[k * 128 + (n - 256)];
    Wt2cat[n * 256 + k] = f2bf(v);
    return;
  }
  i -= 384 * 256;
  if (i < 128 * 128) {                // Wt3n[n][k], n padded 119->128
    int n = i / 128, k = i % 128;
    Wt3n[i] = (n < NT) ? f2bf(nW3[k * NT + n]) : (short)0;
    return;
  }
  i -= 128 * 128;
  if (i < 4 * 128) { int n = i / 128, k = i % 128; Wt3t[i] = f2bf(tW3[k * 4 + n]); return; }
  i -= 512;
  if (i < 3 * 128) { int n = i / 128, k = i % 128; Wt3d[i] = f2bf(dW3[k * 3 + n]); return; }
}

// ---------------- counting sort of edges by src node ----------------
__global__ __launch_bounds__(256) void kzero(int* __restrict__ cnt) {
  cnt[blockIdx.x * 256 + threadIdx.x] = 0;
}
__global__ __launch_bounds__(256) void khist(const int* __restrict__ eidx, int* __restrict__ cnt) {
  int e = blockIdx.x * 256 + threadIdx.x;
  if (e < NEDGES) atomicAdd(&cnt[eidx[e]], 1);
}
__global__ __launch_bounds__(256) void kscan1(int* __restrict__ cnt, int* __restrict__ bsum) {
  __shared__ int s[256];
  const int t = threadIdx.x;
  const int i = blockIdx.x * 256 + t;
  int x = cnt[i];
  s[t] = x;
  __syncthreads();
  #pragma unroll
  for (int off = 1; off < 256; off <<= 1) {
    int y = (t >= off) ? s[t - off] : 0;
    __syncthreads();
    s[t] += y;
    __syncthreads();
  }
  cnt[i] = s[t] - x;                      // in-block exclusive prefix
  if (t == 255) bsum[blockIdx.x] = s[t];  // block total
}
__global__ __launch_bounds__(512) void kscan2(int* __restrict__ bsum) {
  __shared__ int s[512];
  const int t = threadIdx.x;
  int x = (t < 392) ? bsum[t] : 0;
  s[t] = x;
  __syncthreads();
  #pragma unroll
  for (int off = 1; off < 512; off <<= 1) {
    int y = (t >= off) ? s[t - off] : 0;
    __syncthreads();
    s[t] += y;
    __syncthreads();
  }
  if (t < 392) bsum[t] = s[t] - x;        // exclusive block bases
}
__global__ __launch_bounds__(256) void kscatter(
    const int* __restrict__ eidx, int* __restrict__ cnt,
    const int* __restrict__ bsum,
    int* __restrict__ srcs, int* __restrict__ dsts, int* __restrict__ eids) {
  int e = blockIdx.x * 256 + threadIdx.x;
  if (e < NEDGES) {
    int sNode = eidx[e];
    int p = atomicAdd(&cnt[sNode], 1) + bsum[sNode >> 8];
    srcs[p] = sNode;
    dsts[p] = eidx[NEDGES + e];
    eids[p] = e;
  }
}

// ---------------- K1: nodeFeat x [nW1 | tW1_src | tW1_dst | dW1_src | dW1_dst] ----------------
__global__ __launch_bounds__(256) void k1_gemm(
    const short* __restrict__ latent_bf, const short* __restrict__ pos_bf,
    const int* __restrict__ batch, const short* __restrict__ Wtcat,
    const float* __restrict__ nb1, const float* __restrict__ tb1, const float* __restrict__ db1,
    short* __restrict__ h1_node, short* __restrict__ Pall)
{
  __shared__ short As[64 * 40];
  const int t = threadIdx.x;
  const int bm0 = blockIdx.x * 64;
  const int n0 = blockIdx.y * 128;
  const int wid = t >> 6, lane = t & 63;
  const int wm = wid >> 1, wn = wid & 1;
  const int lrow = lane & 15, kq = lane >> 4;

  const int sr = t >> 2, sq = t & 3;
  const int m_stage = bm0 + sr;
  const bool svalid = (m_stage < NNODES);
  const int g = svalid ? batch[m_stage] : 0;

  f4 acc[2][4];
  #pragma unroll
  for (int a = 0; a < 2; ++a)
    #pragma unroll
    for (int b = 0; b < 4; ++b) acc[a][b] = (f4){0.f, 0.f, 0.f, 0.f};

  for (int kc = 0; kc < 9; ++kc) {
    const int k0 = kc * 32;
    short8 av = {0, 0, 0, 0, 0, 0, 0, 0};
    if (svalid) {
      if (k0 < 256)      av = *(const short8*)(latent_bf + g * 256 + k0 + sq * 8);
      else if (sq == 0)  av = *(const short8*)(pos_bf + m_stage * 8);
    }
    *(short8*)(As + sr * 40 + sq * 8) = av;
    __syncthreads();

    short8 af[2];
    #pragma unroll
    for (int mf = 0; mf < 2; ++mf)
      af[mf] = *(const short8*)(As + (wm * 32 + mf * 16 + lrow) * 40 + kq * 8);
    #pragma unroll
    for (int nf = 0; nf < 4; ++nf) {
      const int ncol = n0 + wn * 64 + nf * 16 + lrow;
      short8 bfv = *(const short8*)(Wtcat + ncol * 288 + k0 + kq * 8);
      acc[0][nf] = __builtin_amdgcn_mfma_f32_16x16x32_bf16(af[0], bfv, acc[0][nf], 0, 0, 0);
      acc[1][nf] = __builtin_amdgcn_mfma_f32_16x16x32_bf16(af[1], bfv, acc[1][nf], 0, 0, 0);
    }
    __syncthreads();
  }

  #pragma unroll
  for (int mf = 0; mf < 2; ++mf)
    #pragma unroll
    for (int nf = 0; nf < 4; ++nf) {
      const int nglob = n0 + wn * 64 + nf * 16 + lrow;
      #pragma unroll
      for (int r = 0; r < 4; ++r) {
        const int m = bm0 + wm * 32 + mf * 16 + kq * 4 + r;
        if (m < NNODES) {
          float v = acc[mf][nf][r];
          if (nglob < 256) {
            float h = v + nb1[nglob];
            h1_node[m * 256 + nglob] = f2bf(h > 0.f ? h : 0.f);
          } else {
            const int pc = nglob - 256;
            float vv = v;
            int newc = pc;
            if (pc < 256)       { vv += tb1[pc]; }                        // t_src -> 0:256
            else if (pc < 512)  { newc = pc + 256; }                      // t_dst -> 512:768
            else if (pc < 768)  { vv += db1[pc - 512]; newc = pc - 256; } // d_src -> 256:512
            Pall[m * 1024 + newc] = f2bf(vv);
          }
        }
      }
    }
}

// ---------------- K2: node tail 256 -> 128(relu) -> 119 ----------------
__global__ __launch_bounds__(256) void k2_node_tail(
    const short* __restrict__ h1_node, const short* __restrict__ Wt2cat,
    const short* __restrict__ Wt3n, const float* __restrict__ nb2,
    const float* __restrict__ nb3, float* __restrict__ out_node)
{
  __shared__ short h2s[64 * 136];
  const int t = threadIdx.x;
  const int bm0 = blockIdx.x * 64;
  const int wid = t >> 6, lane = t & 63;
  const int wm = wid >> 1, wn = wid & 1;
  const int lrow = lane & 15, kq = lane >> 4;

  f4 acc[2][4];
  #pragma unroll
  for (int a = 0; a < 2; ++a)
    #pragma unroll
    for (int b = 0; b < 4; ++b) acc[a][b] = (f4){0.f, 0.f, 0.f, 0.f};

  #pragma unroll
  for (int kc = 0; kc < 8; ++kc) {
    short8 af[2];
    #pragma unroll
    for (int mf = 0; mf < 2; ++mf) {
      const int m = bm0 + wm * 32 + mf * 16 + lrow;
      if (m < NNODES) af[mf] = *(const short8*)(h1_node + m * 256 + kc * 32 + kq * 8);
      else            af[mf] = (short8){0, 0, 0, 0, 0, 0, 0, 0};
    }
    #pragma unroll
    for (int nf = 0; nf < 4; ++nf) {
      const int ncol = wn * 64 + nf * 16 + lrow;
      short8 bfv = *(const short8*)(Wt2cat + ncol * 256 + kc * 32 + kq * 8);
      acc[0][nf] = __builtin_amdgcn_mfma_f32_16x16x32_bf16(af[0], bfv, acc[0][nf], 0, 0, 0);
      acc[1][nf] = __builtin_amdgcn_mfma_f32_16x16x32_bf16(af[1], bfv, acc[1][nf], 0, 0, 0);
    }
  }
  #pragma unroll
  for (int mf = 0; mf < 2; ++mf)
    #pragma unroll
    for (int nf = 0; nf < 4; ++nf) {
      const int n = wn * 64 + nf * 16 + lrow;
      #pragma unroll
      for (int r = 0; r < 4; ++r) {
        const int ml = wm * 32 + mf * 16 + kq * 4 + r;
        float h = acc[mf][nf][r] + nb2[n];
        h2s[ml * 136 + n] = f2bf(h > 0.f ? h : 0.f);
      }
    }
  __syncthreads();

  f4 acc2[2][4];
  #pragma unroll
  for (int a = 0; a < 2; ++a)
    #pragma unroll
    for (int b = 0; b < 4; ++b) acc2[a][b] = (f4){0.f, 0.f, 0.f, 0.f};

  #pragma unroll
  for (int kc = 0; kc < 4; ++kc) {
    short8 af[2];
    #pragma unroll
    for (int mf = 0; mf < 2; ++mf)
      af[mf] = *(const short8*)(h2s + (wm * 32 + mf * 16 + lrow) * 136 + kc * 32 + kq * 8);
    #pragma unroll
    for (int nf = 0; nf < 4; ++nf) {
      const int ncol = wn * 64 + nf * 16 + lrow;
      short8 bfv = *(const short8*)(Wt3n + ncol * 128 + kc * 32 + kq * 8);
      acc2[0][nf] = __builtin_amdgcn_mfma_f32_16x16x32_bf16(af[0], bfv, acc2[0][nf], 0, 0, 0);
      acc2[1][nf] = __builtin_amdgcn_mfma_f32_16x16x32_bf16(af[1], bfv, acc2[1][nf], 0, 0, 0);
    }
  }
  #pragma unroll
  for (int mf = 0; mf < 2; ++mf)
    #pragma unroll
    for (int nf = 0; nf < 4; ++nf) {
      const int n = wn * 64 + nf * 16 + lrow;
      #pragma unroll
      for (int r = 0; r < 4; ++r) {
        const int m = bm0 + wm * 32 + mf * 16 + kq * 4 + r;
        if (m < NNODES && n < NT) out_node[m * NT + n] = acc2[mf][nf][r] + nb3[n];
      }
    }
}

// ---------------- K3: src-sorted edges, in-tile src dedup, combined gather ----------------
// Pall layout: [t_src(0:256) | d_src(256:512) | t_dst(512:768) | d_dst(768:1024)].
// Sorted tiles of 32 edges: ~8-10 unique src rows gathered once by "leader" edges
// into LDS; dst rows gathered per-edge straight into registers (issued before any
// barrier). h1 = relu(src+dst) built in regs, staged over the same LDS buffer.
__global__ __launch_bounds__(256) void k3_edge(
    const short* __restrict__ Pall,
    const int* __restrict__ srcs, const int* __restrict__ dsts, const int* __restrict__ eids,
    const short* __restrict__ Wt2cat, const short* __restrict__ Wt3t, const short* __restrict__ Wt3d,
    const float* __restrict__ tb2, const float* __restrict__ tb3,
    const float* __restrict__ db2, const float* __restrict__ db3,
    float* __restrict__ out_t, float* __restrict__ out_d)
{
  __shared__ short buf[32 * 520];              // src-unique rows, then h1 rows (phased)
  __shared__ int slotL[32];
  __shared__ int leadL[32];

  const int t = threadIdx.x;
  const int wid = t >> 6, lane = t & 63;
  // bijective XCD-chunked tile map: 12500 = 4*1563 + 4*1562
  const int xcd = blockIdx.x & 7, chunk = blockIdx.x >> 3;
  const int tile = (xcd < 4) ? xcd * 1563 + chunk : 6252 + (xcd - 4) * 1562 + chunk;
  const int base = tile * 32;
  const int er = t >> 3, j = t & 7;            // gather coords: 8 lanes per edge
  const int lrow = lane & 15, kq = lane >> 4;  // mfma lane coords

  // ---- dedup bookkeeping (wave 0, lanes 0..31) ----
  if (t < 32) {
    int s = srcs[base + t];
    int sp = (t > 0) ? srcs[base + t - 1] : -1;
    int lead = (s != sp) ? 1 : 0;
    unsigned long long m = __ballot(lead != 0);
    int slot = __popcll(m & ((1ull << t) - 1)) - (lead ? 0 : 1);
    slotL[t] = slot;
    leadL[t] = lead;
  }

  // ---- dst gather straight to regs (issues before first barrier) ----
  const int d_idx = dsts[base + er];
  const int s_idx = srcs[base + er];
  const short* Pd = Pall + (size_t)d_idx * 1024 + 512 + j * 8;
  short8 dv[8];
  #pragma unroll
  for (int c = 0; c < 8; ++c) dv[c] = *(const short8*)(Pd + c * 64);
  __syncthreads();                             // slotL/leadL ready

  const int slot = slotL[er];
  // ---- leaders gather unique src rows into LDS ----
  if (leadL[er]) {
    const short* Ps = Pall + (size_t)s_idx * 1024 + j * 8;
    short8 sv[8];
    #pragma unroll
    for (int c = 0; c < 8; ++c) sv[c] = *(const short8*)(Ps + c * 64);
    #pragma unroll
    for (int c = 0; c < 8; ++c)
      *(short8*)(buf + slot * 520 + c * 64 + j * 8) = sv[c];
  }
  __syncthreads();                             // srcU ready

  // ---- combine: h1 = relu(srcU[slot] + dst) in regs ----
  short8 hv[8];
  #pragma unroll
  for (int c = 0; c < 8; ++c) {
    short8 sv = *(const short8*)(buf + slot * 520 + c * 64 + j * 8);
    short8 o;
    #pragma unroll
    for (int x = 0; x < 8; ++x) {
      float f = bf2f(sv[x]) + bf2f(dv[c][x]);
      o[x] = f2bf(f > 0.f ? f : 0.f);
    }
    hv[c] = o;
  }
  __syncthreads();                             // all srcU reads done before overwrite

  #pragma unroll
  for (int c = 0; c < 8; ++c)
    *(short8*)(buf + er * 520 + c * 64 + j * 8) = hv[c];
  __syncthreads();                             // h1 ready

  // ---- layer2 TYPE: h1[:,0:256] @ tW2 (Wt2cat rows 128:256). wave owns 32 N-cols.
  f4 acc_t[2][2];
  #pragma unroll
  for (int a = 0; a < 2; ++a)
    #pragma unroll
    for (int b = 0; b < 2; ++b) acc_t[a][b] = (f4){0.f, 0.f, 0.f, 0.f};
  #pragma unroll
  for (int kc = 0; kc < 8; ++kc) {
    short8 a0 = *(const short8*)(buf + lrow * 520 + kc * 32 + kq * 8);
    short8 a1 = *(const short8*)(buf + (16 + lrow) * 520 + kc * 32 + kq * 8);
    #pragma unroll
    for (int nf = 0; nf < 2; ++nf) {
      short8 bfv = *(const short8*)(Wt2cat + (128 + wid * 32 + nf * 16 + lrow) * 256 + kc * 32 + kq * 8);
      acc_t[0][nf] = __builtin_amdgcn_mfma_f32_16x16x32_bf16(a0, bfv, acc_t[0][nf], 0, 0, 0);
      acc_t[1][nf] = __builtin_amdgcn_mfma_f32_16x16x32_bf16(a1, bfv, acc_t[1][nf], 0, 0, 0);
    }
  }
  __syncthreads();   // all waves done reading h1_t before overwrite

  // ---- h2_t = relu(acc_t + tb2) -> cols 0:128 (over dead h1_t) ----
  #pragma unroll
  for (int mf = 0; mf < 2; ++mf)
    #pragma unroll
    for (int nf = 0; nf < 2; ++nf) {
      const int n2 = wid * 32 + nf * 16 + lrow;
      const float bb = tb2[n2];
      #pragma unroll
      for (int rr = 0; rr < 4; ++rr) {
        float h = acc_t[mf][nf][rr] + bb;
        buf[(mf * 16 + kq * 4 + rr) * 520 + n2] = f2bf(h > 0.f ? h : 0.f);
      }
    }

  // ---- layer2 DIR: h1[:,256:512] @ dW2 (Wt2cat rows 256:384) ----
  f4 acc_d[2][2];
  #pragma unroll
  for (int a = 0; a < 2; ++a)
    #pragma unroll
    for (int b = 0; b < 2; ++b) acc_d[a][b] = (f4){0.f, 0.f, 0.f, 0.f};
  #pragma unroll
  for (int kc = 0; kc < 8; ++kc) {
    short8 a0 = *(const short8*)(buf + lrow * 520 + 256 + kc * 32 + kq * 8);
    short8 a1 = *(const short8*)(buf + (16 + lrow) * 520 + 256 + kc * 32 + kq * 8);
    #pragma unroll
    for (int nf = 0; nf < 2; ++nf) {
      short8 bfv = *(const short8*)(Wt2cat + (256 + wid * 32 + nf * 16 + lrow) * 256 + kc * 32 + kq * 8);
      acc_d[0][nf] = __builtin_amdgcn_mfma_f32_16x16x32_bf16(a0, bfv, acc_d[0][nf], 0, 0, 0);
      acc_d[1][nf] = __builtin_amdgcn_mfma_f32_16x16x32_bf16(a1, bfv, acc_d[1][nf], 0, 0, 0);
    }
  }

  // ---- h2_d = relu(acc_d + db2) -> cols 128:256 (over dead h1_t upper half) ----
  #pragma unroll
  for (int mf = 0; mf < 2; ++mf)
    #pragma unroll
    for (int nf = 0; nf < 2; ++nf) {
      const int n2 = wid * 32 + nf * 16 + lrow;
      const float bb = db2[n2];
      #pragma unroll
      for (int rr = 0; rr < 4; ++rr) {
        float h = acc_d[mf][nf][rr] + bb;
        buf[(mf * 16 + kq * 4 + rr) * 520 + 128 + n2] = f2bf(h > 0.f ? h : 0.f);
      }
    }
  __syncthreads();

  // ---- layer 3: 8 threads/edge, n=0..3 type, n=4..6 dir ----
  {
    const int e2 = t >> 3, n = t & 7;
    if (n < 7) {
      const bool isT = (n < 4);
      const int col = isT ? n : n - 4;
      const short* W3 = isT ? (Wt3t + col * 128) : (Wt3d + col * 128);
      const int bb = e2 * 520 + (isT ? 0 : 128);
      float s = 0.f;
      #pragma unroll
      for (int kk = 0; kk < 16; ++kk) {
        short8 hvv = *(const short8*)(buf + bb + kk * 8);
        short8 wv = *(const short8*)(W3 + kk * 8);
        #pragma unroll
        for (int x = 0; x < 8; ++x) s += bf2f(hvv[x]) * bf2f(wv[x]);
      }
      const int eid2 = eids[base + e2];
      if (isT) out_t[eid2 * 4 + col] = s + tb3[col];
      else     out_d[eid2 * 3 + col] = s + db3[col];
    }
  }
}

extern "C" void kernel_launch(void* const* d_in, const int* in_sizes, int n_in,
                              void* d_out, int out_size, void* d_ws, size_t ws_size,
                              hipStream_t stream)
{
  const float* lat = (const float*)d_in[0];
  const float* pos = (const float*)d_in[1];
  const int* batch = (const int*)d_in[2];
  const int* eidx  = (const int*)d_in[3];
  const float* nW1 = (const float*)d_in[4];  const float* nb1 = (const float*)d_in[5];
  const float* nW2 = (const float*)d_in[6];  const float* nb2 = (const float*)d_in[7];
  const float* nW3 = (const float*)d_in[8];  const float* nb3 = (const float*)d_in[9];
  const float* tW1 = (const float*)d_in[10]; const float* tb1 = (const float*)d_in[11];
  const float* tW2 = (const float*)d_in[12]; const float* tb2 = (const float*)d_in[13];
  const float* tW3 = (const float*)d_in[14]; const float* tb3 = (const float*)d_in[15];
  const float* dW1 = (const float*)d_in[16]; const float* db1 = (const float*)d_in[17];
  const float* dW2 = (const float*)d_in[18]; const float* db2 = (const float*)d_in[19];
  const float* dW3 = (const float*)d_in[20]; const float* db3 = (const float*)d_in[21];

  char* ws = (char*)d_ws;
  short* latent_bf = (short*)(ws + 0);          //   1,048,576 B
  short* pos_bf    = (short*)(ws + 1048576);    //   1,600,000 B
  short* Wtcat     = (short*)(ws + 2648576);    //     737,280 B
  short* Wt2cat    = (short*)(ws + 3385856);    //     196,608 B
  short* Wt3n      = (short*)(ws + 3582464);    //      32,768 B
  short* Wt3t      = (short*)(ws + 3615232);    //       1,024 B
  short* Wt3d      = (short*)(ws + 3616256);    //       1,024 B (768 used)
  short* h1_node   = (short*)(ws + 3617280);    //  51,200,000 B
  short* Pall      = (short*)(ws + 54817280);   // 204,800,000 B  -> total ~259.6 MB
  // sort scratch lives inside the h1_node region (dead once k2 finishes):
  int* srcs = (int*)(ws + 3617280);             //   1,600,000 B
  int* dsts = (int*)(ws + 3617280 + 1600000);   //   1,600,000 B
  int* eids = (int*)(ws + 3617280 + 3200000);   //   1,600,000 B
  int* cnt  = (int*)(ws + 3617280 + 4800000);   //     401,408 B (NBUCK)
  int* bsum = (int*)(ws + 3617280 + 5201408);   //       1,568 B (392)

  float* out_node = (float*)d_out;
  float* out_t = out_node + (size_t)NNODES * NT;
  float* out_d = out_t + (size_t)NEDGES * 4;

  prep_kernel<<<7065, 256, 0, stream>>>(lat, pos, nW1, tW1, dW1, nW2, tW2, dW2,
                                        nW3, tW3, dW3, latent_bf, pos_bf, Wtcat,
                                        Wt2cat, Wt3n, Wt3t, Wt3d);
  k1_gemm<<<dim3(1563, 10), 256, 0, stream>>>(latent_bf, pos_bf, batch, Wtcat,
                                              nb1, tb1, db1, h1_node, Pall);
  k2_node_tail<<<1563, 256, 0, stream>>>(h1_node, Wt2cat, Wt3n, nb2, nb3, out_node);
  // counting sort of edges by src (overwrites h1_node region, now dead)
  kzero<<<NBUCK / 256, 256, 0, stream>>>(cnt);
  khist<<<1563, 256, 0, stream>>>(eidx, cnt);
  kscan1<<<392, 256, 0, stream>>>(cnt, bsum);
  kscan2<<<1, 512, 0, stream>>>(bsum);
  kscatter<<<1563, 256, 0, stream>>>(eidx, cnt, bsum, srcs, dsts, eids);
  k3_edge<<<NT3, 256, 0, stream>>>(Pall, srcs, dsts, eids, Wt2cat, Wt3t, Wt3d,
                                   tb2, tb3, db2, db3, out_t, out_d);
}